// Round 11
// baseline (595.804 us; speedup 1.0000x reference)
//
#include <hip/hip_runtime.h>
#include <math.h>

#define BB 16
#define TT 96
#define HH 31
#define WW 64
#define BT (BB*TT)
#define C1 16
#define C2 32
#define LH 64
#define NC 10

typedef _Float16 half8 __attribute__((ext_vector_type(8)));
typedef float floatx16 __attribute__((ext_vector_type(16)));

// split-tile conv1-output geometry: 18 local rows x XPAD(66) positions,
// 32B per position (16ch fp16). 38KB LDS -> 4 blocks/CU -> 8 waves/SIMD.
#define XPAD 66
#define LROWS 18
#define SXB2 (LROWS*XPAD*32 + 128)

// XOR-swizzle: spread the 32B-stride position layout across LDS bank groups.
// Applied identically on write and read.
__device__ __forceinline__ int swz(int byte) {
    return byte ^ (((byte >> 7) & 7) << 4);
}

// ---------------------------------------------------------------------------
// K1: conv1(fp32) -> relu -> LDS fp16 ch-last -> conv2 as 9 tap-GEMMs on
// v_mfma_f32_32x32x16_f16 -> relu -> partial avgpool sum.
// Grid (BT, 2 parts, 2 y-halves). Half 0: conv2 y=0..15 (conv1 rows -1..16,
// local r=y+1); half 1: y=16..30 (conv1 rows 15..31, local r=y-15).
// Partial pool sums go to poolp[half]; lstm_prep adds the halves (no atomics).
// __launch_bounds__(512,8): pin the 64-VGPR codegen the compiler already
// chooses -> 32 waves/CU when LDS allows 4 blocks.
// ---------------------------------------------------------------------------
__global__ __launch_bounds__(512, 8)
void conv_pool_mfma(const float* __restrict__ xr, const float* __restrict__ xi,
                    const float* __restrict__ w1r, const float* __restrict__ b1r,
                    const float* __restrict__ w1i, const float* __restrict__ b1i,
                    const float* __restrict__ w2r, const float* __restrict__ b2r,
                    const float* __restrict__ w2i, const float* __restrict__ b2i,
                    float* __restrict__ poolp_r, float* __restrict__ poolp_m)
{
    __shared__ __align__(128) unsigned char s_x[SXB2];
    __shared__ float s_pool[C2];

    const int tid  = threadIdx.x;
    const int lane = tid & 63;
    const int img  = blockIdx.x;
    const int part = blockIdx.y;
    const int hf   = blockIdx.z;     // 0: y 0..15, 1: y 16..30

    const float* xg = (part ? xi : xr) + img*(HH*WW);
    const float* w1 = part ? w1i : w1r;
    const float* b1 = part ? b1i : b1r;
    const float* w2 = part ? w2i : w2r;
    const float* b2 = part ? b2i : b2r;
    float* poolo = (part ? poolp_m : poolp_r) + (hf*BT + img)*C2;

    if (tid < C2) s_pool[tid] = 0.f;

    // zero: one full border row (local 0 for hf=0, local 16 for hf=1) and
    // the xp=0/65 columns of all 18 local rows.
    if (tid < 102) {
        int pos;
        if (tid < 66) pos = (hf ? 16 : 0)*XPAD + tid;
        else {
            int i = tid - 66;                    // 0..35 -> rows 0..17
            pos = (i >> 1)*XPAD + ((i & 1) ? 65 : 0);
        }
        *reinterpret_cast<int4*>(s_x + swz(pos*32))      = make_int4(0,0,0,0);
        *reinterpret_cast<int4*>(s_x + swz(pos*32 + 16)) = make_int4(0,0,0,0);
    }

    // ---- conv1: task = (row, 4-wide x chunk); 3x6 patch; 2 passes of 8ch.
    // hf=0: rows y=0..16 -> local 1..17; hf=1: rows y=15..30 -> local 0..15.
    {
        const int nr = hf ? 16 : 17;
        if (tid < nr*16) {
            const int ry = tid >> 4;
            const int y  = hf ? (15 + ry) : ry;
            const int lr = hf ? ry : (ry + 1);
            const int x0 = (tid & 15) << 2;
            float patch[3][6];
            #pragma unroll
            for (int ky = 0; ky < 3; ++ky) {
                int row = y + ky - 1;
                #pragma unroll
                for (int j = 0; j < 6; ++j) {
                    int col = x0 + j - 1;
                    patch[ky][j] = (row >= 0 && row < HH && col >= 0 && col < WW)
                                     ? xg[row*WW + col] : 0.f;
                }
            }
            #pragma unroll
            for (int p = 0; p < 2; ++p) {
                float acc[8][4];
                #pragma unroll
                for (int ch = 0; ch < 8; ++ch) {
                    float bb = b1[p*8 + ch];
                    #pragma unroll
                    for (int j = 0; j < 4; ++j) acc[ch][j] = bb;
                }
                #pragma unroll
                for (int ky = 0; ky < 3; ++ky)
                    #pragma unroll
                    for (int kx = 0; kx < 3; ++kx) {
                        #pragma unroll
                        for (int ch = 0; ch < 8; ++ch) {
                            float wv = w1[(p*8 + ch)*9 + ky*3 + kx]; // SGPR
                            #pragma unroll
                            for (int j = 0; j < 4; ++j)
                                acc[ch][j] += patch[ky][kx + j] * wv;
                        }
                    }
                #pragma unroll
                for (int j = 0; j < 4; ++j) {
                    half8 v;
                    #pragma unroll
                    for (int ch = 0; ch < 8; ++ch)
                        v[ch] = (_Float16)fmaxf(acc[ch][j], 0.f);
                    int pos = lr*XPAD + (x0 + j + 1);
                    *reinterpret_cast<half8*>(s_x + swz(pos*32 + p*16)) = v;
                }
            }
        }
    }

    // ---- conv2 A-fragments + bias ----
    const int oc  = lane & 31;
    const int icb = (lane >> 5) * 8;
    half8 af[9];
    #pragma unroll
    for (int t = 0; t < 9; ++t) {
        half8 v;
        #pragma unroll
        for (int i = 0; i < 8; ++i)
            v[i] = (_Float16)w2[(oc*C1 + icb + i)*9 + t];
        af[t] = v;
    }
    float bias[16];
    #pragma unroll
    for (int r = 0; r < 16; ++r)
        bias[r] = b2[(r & 3) + 8*(r >> 2) + 4*(lane >> 5)];

    __syncthreads();

    // ---- conv2 + relu + partial pool: hf=0 -> 32 tiles, hf=1 -> 30 tiles.
    // conv2 at tile-row ty reads local rows ty..ty+2 for both halves.
    float pool[16];
    #pragma unroll
    for (int r = 0; r < 16; ++r) pool[r] = 0.f;

    const int wav = tid >> 6;
    const int halfoff = (lane >> 5) << 4;
    const int ntiles = hf ? 30 : 32;

    #define LDB(dst, ky, kx) do { \
        int byte_ = (pbase + (ky)*XPAD + (kx))*32 + halfoff; \
        dst = *reinterpret_cast<const half8*>(s_x + swz(byte_)); } while (0)

    for (int tile = wav; tile < ntiles; tile += 8) {
        int ty = tile >> 1;
        int x0 = (tile & 1) * 32;
        int pbase = ty*XPAD + x0 + (lane & 31);
        floatx16 acc;
        #pragma unroll
        for (int r = 0; r < 16; ++r) acc[r] = bias[r];

        half8 r0a, r0b, r0c, r1a, r1b, r1c, r2a, r2b, r2c;
        LDB(r0a, 0, 0); LDB(r0b, 0, 1); LDB(r0c, 0, 2);
        LDB(r1a, 1, 0); LDB(r1b, 1, 1); LDB(r1c, 1, 2);
        acc = __builtin_amdgcn_mfma_f32_32x32x16_f16(af[0], r0a, acc, 0, 0, 0);
        acc = __builtin_amdgcn_mfma_f32_32x32x16_f16(af[1], r0b, acc, 0, 0, 0);
        acc = __builtin_amdgcn_mfma_f32_32x32x16_f16(af[2], r0c, acc, 0, 0, 0);
        LDB(r2a, 2, 0); LDB(r2b, 2, 1); LDB(r2c, 2, 2);
        acc = __builtin_amdgcn_mfma_f32_32x32x16_f16(af[3], r1a, acc, 0, 0, 0);
        acc = __builtin_amdgcn_mfma_f32_32x32x16_f16(af[4], r1b, acc, 0, 0, 0);
        acc = __builtin_amdgcn_mfma_f32_32x32x16_f16(af[5], r1c, acc, 0, 0, 0);
        acc = __builtin_amdgcn_mfma_f32_32x32x16_f16(af[6], r2a, acc, 0, 0, 0);
        acc = __builtin_amdgcn_mfma_f32_32x32x16_f16(af[7], r2b, acc, 0, 0, 0);
        acc = __builtin_amdgcn_mfma_f32_32x32x16_f16(af[8], r2c, acc, 0, 0, 0);

        #pragma unroll
        for (int r = 0; r < 16; ++r) pool[r] += fmaxf(acc[r], 0.f);
    }
    #undef LDB

    #pragma unroll
    for (int m = 1; m <= 16; m <<= 1) {
        #pragma unroll
        for (int r = 0; r < 16; ++r) pool[r] += __shfl_xor(pool[r], m, 64);
    }
    if ((lane & 31) == 0) {
        #pragma unroll
        for (int r = 0; r < 16; ++r)
            atomicAdd(&s_pool[(r & 3) + 8*(r >> 2) + 4*(lane >> 5)], pool[r]);
    }
    __syncthreads();
    if (tid < C2) poolo[tid] = s_pool[tid];     // raw partial; prep scales
}

// ---------------------------------------------------------------------------
// K2a: prep — one block per (b,t). Sums the two pool halves, then
// feat[128] -> fused[64] -> gates_x[256]. 1536 blocks = full-GPU parallel.
// ---------------------------------------------------------------------------
__device__ __forceinline__ float sigm(float x){ return 1.f/(1.f + __expf(-x)); }
__device__ __forceinline__ float ftanh(float x){
    float xc = fminf(fmaxf(x, -15.f), 15.f);
    float e = __expf(2.f*xc);
    return (e - 1.f)/(e + 1.f);
}

__global__ __launch_bounds__(256)
void lstm_prep(const float* __restrict__ poolp_r, const float* __restrict__ poolp_m,
               const float* __restrict__ fus_w, const float* __restrict__ fus_b,
               const float* __restrict__ wf_ih,
               const float* __restrict__ bf_ih, const float* __restrict__ bf_hh,
               float* __restrict__ fusedg, float* __restrict__ gates_x)
{
    __shared__ __align__(16) float s_feat[128];
    __shared__ __align__(16) float s_fused[64];
    const int bt  = blockIdx.x;          // b*96 + t
    const int tid = threadIdx.x;

    if (tid < 32) {
        float r = (poolp_r[bt*C2 + tid] + poolp_r[(BT + bt)*C2 + tid]) * (1.f/1984.f);
        float m = (poolp_m[bt*C2 + tid] + poolp_m[(BT + bt)*C2 + tid]) * (1.f/1984.f);
        s_feat[tid]      = r;
        s_feat[32 + tid] = m;
        s_feat[64 + tid] = sqrtf(r*r + m*m);
        s_feat[96 + tid] = atan2f(m, r);
    }
    __syncthreads();

    if (tid < 64) {
        float acc = fus_b[tid];
        const float4* wv = reinterpret_cast<const float4*>(fus_w + tid*128);
        float a0=0.f, a1=0.f, a2=0.f, a3=0.f;
        #pragma unroll
        for (int q = 0; q < 32; ++q) {
            float4 w = wv[q];
            float4 f = *reinterpret_cast<const float4*>(s_feat + q*4);
            a0 += w.x*f.x; a1 += w.y*f.y; a2 += w.z*f.z; a3 += w.w*f.w;
        }
        float v = fmaxf(acc + (a0+a1) + (a2+a3), 0.f);
        s_fused[tid] = v;
        fusedg[bt*64 + tid] = v;
    }
    __syncthreads();

    {
        float acc = bf_ih[tid] + bf_hh[tid];
        const float4* wv = reinterpret_cast<const float4*>(wf_ih + tid*64);
        float a0=0.f, a1=0.f, a2=0.f, a3=0.f;
        #pragma unroll
        for (int q = 0; q < 16; ++q) {
            float4 w = wv[q];
            float4 f = *reinterpret_cast<const float4*>(s_fused + q*4);
            a0 += w.x*f.x; a1 += w.y*f.y; a2 += w.z*f.z; a3 += w.w*f.w;
        }
        gates_x[bt*256 + tid] = acc + (a0+a1) + (a2+a3);
    }
}

// ---------------------------------------------------------------------------
// K2b: scan (unchanged from round 10). Blocks 0..15: forward recurrence,
// one barrier/step, gates assembled in-wave via 3x shfl_xor, s_h dbuf.
// Blocks 16..31: backward LSTM = one step on fused[b,len-1] from zero state.
// ---------------------------------------------------------------------------
__global__ __launch_bounds__(256, 1)
void lstm_scan(const float* __restrict__ gates_x, const float* __restrict__ fusedg,
               const int* __restrict__ lengths,
               const float* __restrict__ wf_hh,
               const float* __restrict__ wb_ih,
               const float* __restrict__ bb_ih, const float* __restrict__ bb_hh,
               float* __restrict__ last_f, float* __restrict__ hb0)
{
    const int tid = threadIdx.x;
    const int b   = blockIdx.x & 15;
    const int len = lengths[b];

    if (blockIdx.x < 16) {
        __shared__ __align__(16) float s_h[2][64];
        const int ln = tid & 63;
        const int w  = tid >> 6;
        const int q  = ln >> 4;            // gate: 0=i 1=f 2=g 3=o
        const int u  = w*16 + (ln & 15);   // hidden unit
        const int g  = q*64 + u;           // gate row

        float whh[64];
        #pragma unroll
        for (int j = 0; j < 64; j += 4) {
            float4 a = *reinterpret_cast<const float4*>(wf_hh + g*64 + j);
            whh[j]=a.x; whh[j+1]=a.y; whh[j+2]=a.z; whh[j+3]=a.w;
        }
        if (q == 0) s_h[0][u] = 0.f;
        __syncthreads();

        const float* gxp = gates_x + (b*TT)*256 + g;
        float gx = gxp[0];
        float creg = 0.f;
        for (int t = 0; t < TT; ++t) {
            float gxn = (t+1 < TT) ? gxp[(t+1)*256] : 0.f;

            const int cur = t & 1;
            float a0=0.f, a1=0.f, a2=0.f, a3=0.f;
            #pragma unroll
            for (int j = 0; j < 64; j += 4) {
                float4 hv = *reinterpret_cast<const float4*>(&s_h[cur][j]);
                a0 += whh[j]*hv.x;   a1 += whh[j+1]*hv.y;
                a2 += whh[j+2]*hv.z; a3 += whh[j+3]*hv.w;
            }
            float acc = gx + (a0+a1) + (a2+a3);

            float p1 = __shfl_xor(acc, 16, 64);   // gate q^1
            float p2 = __shfl_xor(acc, 32, 64);   // gate q^2
            float p3 = __shfl_xor(p1,  32, 64);   // gate q^3
            float g0 = (q==0)?acc : (q==1)?p1 : (q==2)?p2 : p3;
            float g1 = (q==1)?acc : (q==0)?p1 : (q==3)?p2 : p3;
            float g2 = (q==2)?acc : (q==3)?p1 : (q==0)?p2 : p3;
            float g3 = (q==3)?acc : (q==2)?p1 : (q==1)?p2 : p3;

            creg = sigm(g1)*creg + sigm(g0)*ftanh(g2);
            float h = sigm(g3)*ftanh(creg);

            if (q == 0) {
                s_h[cur^1][u] = h;
                if (t == len-1) last_f[b*64 + u] = h;
            }
            gx = gxn;
            __syncthreads();
        }
    } else {
        __shared__ __align__(16) float s_f[64];
        __shared__ float s_g[256];
        if (tid < 64) s_f[tid] = fusedg[(b*TT + (len-1))*64 + tid];
        __syncthreads();
        {
            float acc = bb_ih[tid] + bb_hh[tid];
            const float4* wv = reinterpret_cast<const float4*>(wb_ih + tid*64);
            float a0=0.f, a1=0.f, a2=0.f, a3=0.f;
            #pragma unroll
            for (int qq = 0; qq < 16; ++qq) {
                float4 wvv = wv[qq];
                float4 f = *reinterpret_cast<const float4*>(s_f + qq*4);
                a0 += wvv.x*f.x; a1 += wvv.y*f.y; a2 += wvv.z*f.z; a3 += wvv.w*f.w;
            }
            s_g[tid] = acc + (a0+a1) + (a2+a3);
        }
        __syncthreads();
        if (tid < 64) {
            float iv = sigm(s_g[tid]);            // f gate irrelevant: c0 = 0
            float gv = ftanh(s_g[128+tid]);
            float ov = sigm(s_g[192+tid]);
            hb0[b*64 + tid] = ov*ftanh(iv*gv);
        }
    }
}

// ---------------------------------------------------------------------------
// K3: out[b,k] = fc_b[k] + last_f[b,:].fc_w[k,0:64] + hb0[b,:].fc_w[k,64:128]
// ---------------------------------------------------------------------------
__global__ __launch_bounds__(256)
void final_fc_kernel(const float* __restrict__ last_f, const float* __restrict__ hb0,
                     const float* __restrict__ fc_w, const float* __restrict__ fc_b,
                     float* __restrict__ out)
{
    int t = threadIdx.x;
    if (t >= BB*NC) return;
    int b = t / NC, k = t % NC;
    float acc = fc_b[k];
    const float* w = fc_w + k*128;
    #pragma unroll
    for (int j = 0; j < 64; ++j) acc += last_f[b*64+j]*w[j];
    #pragma unroll
    for (int j = 0; j < 64; ++j) acc += hb0[b*64+j]*w[64+j];
    out[b*NC + k] = acc;
}

extern "C" void kernel_launch(void* const* d_in, const int* in_sizes, int n_in,
                              void* d_out, int out_size, void* d_ws, size_t ws_size,
                              hipStream_t stream)
{
    const float* x_real = (const float*)d_in[0];
    const float* x_imag = (const float*)d_in[1];
    const int*   lengths= (const int*)d_in[2];
    const float* c1r_w = (const float*)d_in[3];
    const float* c1r_b = (const float*)d_in[4];
    const float* c1i_w = (const float*)d_in[5];
    const float* c1i_b = (const float*)d_in[6];
    const float* c2r_w = (const float*)d_in[7];
    const float* c2r_b = (const float*)d_in[8];
    const float* c2i_w = (const float*)d_in[9];
    const float* c2i_b = (const float*)d_in[10];
    const float* fus_w = (const float*)d_in[11];
    const float* fus_b = (const float*)d_in[12];
    const float* wf_ih = (const float*)d_in[13];
    const float* wf_hh = (const float*)d_in[14];
    const float* bf_ih = (const float*)d_in[15];
    const float* bf_hh = (const float*)d_in[16];
    const float* wb_ih = (const float*)d_in[17];
    const float* wb_hh = (const float*)d_in[18];
    const float* bb_ih = (const float*)d_in[19];
    const float* bb_hh = (const float*)d_in[20];
    const float* fc_w  = (const float*)d_in[21];
    const float* fc_b  = (const float*)d_in[22];
    float* out = (float*)d_out;

    // ws layout (floats): poolp_r[2*BT*C2] | poolp_m[2*BT*C2] | fusedg[BT*64]
    //                   | gates_x[BT*256] | last_f | hb0   (~2.8 MB)
    float* ws      = (float*)d_ws;
    float* poolp_r = ws;
    float* poolp_m = poolp_r + 2*BT*C2;
    float* fusedg  = poolp_m + 2*BT*C2;
    float* gates_x = fusedg  + BT*64;
    float* last_f  = gates_x + BT*256;
    float* hb0     = last_f  + BB*LH;

    conv_pool_mfma<<<dim3(BT, 2, 2), 512, 0, stream>>>(
        x_real, x_imag, c1r_w, c1r_b, c1i_w, c1i_b,
        c2r_w, c2r_b, c2i_w, c2i_b, poolp_r, poolp_m);

    lstm_prep<<<BT, 256, 0, stream>>>(poolp_r, poolp_m, fus_w, fus_b,
                                      wf_ih, bf_ih, bf_hh, fusedg, gates_x);

    lstm_scan<<<32, 256, 0, stream>>>(gates_x, fusedg, lengths, wf_hh,
                                      wb_ih, bb_ih, bb_hh, last_f, hb0);

    final_fc_kernel<<<1, 256, 0, stream>>>(last_f, hb0, fc_w, fc_b, out);
}

// Round 13
// 348.027 us; speedup vs baseline: 1.7119x; 1.7119x over previous
//
#include <hip/hip_runtime.h>
#include <math.h>

#define BB 16
#define TT 96
#define HH 31
#define WW 64
#define BT (BB*TT)
#define C1 16
#define C2 32
#define LH 64
#define NC 10

typedef _Float16 half8 __attribute__((ext_vector_type(8)));
typedef float floatx16 __attribute__((ext_vector_type(16)));

// split-tile conv1-output geometry: 18 local rows x XPAD(66) positions,
// 32B per position (16ch fp16). 38.4KB LDS -> 4 blocks/CU when VGPR<=64.
#define XPAD 66
#define LROWS 18
#define SXB2 (LROWS*XPAD*32 + 128)

// XOR-swizzle: spread the 32B-stride position layout across LDS bank groups.
// Applied identically on write and read.
__device__ __forceinline__ int swz(int byte) {
    return byte ^ (((byte >> 7) & 7) << 4);
}

// ---------------------------------------------------------------------------
// K1: conv1(fp32) -> relu -> LDS fp16 ch-last -> conv2 as 9 tap-GEMMs on
// v_mfma_f32_32x32x16_f16 -> relu -> partial avgpool sum.
// Grid (BT, 2 parts, 2 y-halves); 38.4KB LDS tile per block.
// __launch_bounds__(512,2): round-11's (512,8) forced a 32-VGPR allocation
// and 1.5GB of scratch spill traffic (FETCH 862MB). (512,2) compiles this
// register shape to 64 VGPR with zero spill (round-10 evidence), and 64 VGPR
// + 38.4KB LDS -> 4 blocks/CU = 8 waves/SIMD via LDS limit alone.
// ---------------------------------------------------------------------------
__global__ __launch_bounds__(512, 2)
void conv_pool_mfma(const float* __restrict__ xr, const float* __restrict__ xi,
                    const float* __restrict__ w1r, const float* __restrict__ b1r,
                    const float* __restrict__ w1i, const float* __restrict__ b1i,
                    const float* __restrict__ w2r, const float* __restrict__ b2r,
                    const float* __restrict__ w2i, const float* __restrict__ b2i,
                    float* __restrict__ poolp_r, float* __restrict__ poolp_m)
{
    __shared__ __align__(128) unsigned char s_x[SXB2];
    __shared__ float s_pool[C2];

    const int tid  = threadIdx.x;
    const int lane = tid & 63;
    const int img  = blockIdx.x;
    const int part = blockIdx.y;
    const int hf   = blockIdx.z;     // 0: y 0..15, 1: y 16..30

    const float* xg = (part ? xi : xr) + img*(HH*WW);
    const float* w1 = part ? w1i : w1r;
    const float* b1 = part ? b1i : b1r;
    const float* w2 = part ? w2i : w2r;
    const float* b2 = part ? b2i : b2r;
    float* poolo = (part ? poolp_m : poolp_r) + (hf*BT + img)*C2;

    if (tid < C2) s_pool[tid] = 0.f;

    // zero: one full border row (local 0 for hf=0, local 16 for hf=1) and
    // the xp=0/65 columns of all 18 local rows.
    if (tid < 102) {
        int pos;
        if (tid < 66) pos = (hf ? 16 : 0)*XPAD + tid;
        else {
            int i = tid - 66;                    // 0..35 -> rows 0..17
            pos = (i >> 1)*XPAD + ((i & 1) ? 65 : 0);
        }
        *reinterpret_cast<int4*>(s_x + swz(pos*32))      = make_int4(0,0,0,0);
        *reinterpret_cast<int4*>(s_x + swz(pos*32 + 16)) = make_int4(0,0,0,0);
    }

    // ---- conv1: task = (row, 4-wide x chunk); 3x6 patch; 2 passes of 8ch.
    // hf=0: rows y=0..16 -> local 1..17; hf=1: rows y=15..30 -> local 0..15.
    {
        const int nr = hf ? 16 : 17;
        if (tid < nr*16) {
            const int ry = tid >> 4;
            const int y  = hf ? (15 + ry) : ry;
            const int lr = hf ? ry : (ry + 1);
            const int x0 = (tid & 15) << 2;
            float patch[3][6];
            #pragma unroll
            for (int ky = 0; ky < 3; ++ky) {
                int row = y + ky - 1;
                #pragma unroll
                for (int j = 0; j < 6; ++j) {
                    int col = x0 + j - 1;
                    patch[ky][j] = (row >= 0 && row < HH && col >= 0 && col < WW)
                                     ? xg[row*WW + col] : 0.f;
                }
            }
            #pragma unroll
            for (int p = 0; p < 2; ++p) {
                float acc[8][4];
                #pragma unroll
                for (int ch = 0; ch < 8; ++ch) {
                    float bb = b1[p*8 + ch];
                    #pragma unroll
                    for (int j = 0; j < 4; ++j) acc[ch][j] = bb;
                }
                #pragma unroll
                for (int ky = 0; ky < 3; ++ky)
                    #pragma unroll
                    for (int kx = 0; kx < 3; ++kx) {
                        #pragma unroll
                        for (int ch = 0; ch < 8; ++ch) {
                            float wv = w1[(p*8 + ch)*9 + ky*3 + kx]; // SGPR
                            #pragma unroll
                            for (int j = 0; j < 4; ++j)
                                acc[ch][j] += patch[ky][kx + j] * wv;
                        }
                    }
                #pragma unroll
                for (int j = 0; j < 4; ++j) {
                    half8 v;
                    #pragma unroll
                    for (int ch = 0; ch < 8; ++ch)
                        v[ch] = (_Float16)fmaxf(acc[ch][j], 0.f);
                    int pos = lr*XPAD + (x0 + j + 1);
                    *reinterpret_cast<half8*>(s_x + swz(pos*32 + p*16)) = v;
                }
            }
        }
    }

    // ---- conv2 A-fragments + bias ----
    const int oc  = lane & 31;
    const int icb = (lane >> 5) * 8;
    half8 af[9];
    #pragma unroll
    for (int t = 0; t < 9; ++t) {
        half8 v;
        #pragma unroll
        for (int i = 0; i < 8; ++i)
            v[i] = (_Float16)w2[(oc*C1 + icb + i)*9 + t];
        af[t] = v;
    }
    float bias[16];
    #pragma unroll
    for (int r = 0; r < 16; ++r)
        bias[r] = b2[(r & 3) + 8*(r >> 2) + 4*(lane >> 5)];

    __syncthreads();

    // ---- conv2 + relu + partial pool: hf=0 -> 32 tiles, hf=1 -> 30 tiles.
    float pool[16];
    #pragma unroll
    for (int r = 0; r < 16; ++r) pool[r] = 0.f;

    const int wav = tid >> 6;
    const int halfoff = (lane >> 5) << 4;
    const int ntiles = hf ? 30 : 32;

    #define LDB(dst, ky, kx) do { \
        int byte_ = (pbase + (ky)*XPAD + (kx))*32 + halfoff; \
        dst = *reinterpret_cast<const half8*>(s_x + swz(byte_)); } while (0)

    for (int tile = wav; tile < ntiles; tile += 8) {
        int ty = tile >> 1;
        int x0 = (tile & 1) * 32;
        int pbase = ty*XPAD + x0 + (lane & 31);
        floatx16 acc;
        #pragma unroll
        for (int r = 0; r < 16; ++r) acc[r] = bias[r];

        half8 r0a, r0b, r0c, r1a, r1b, r1c, r2a, r2b, r2c;
        LDB(r0a, 0, 0); LDB(r0b, 0, 1); LDB(r0c, 0, 2);
        LDB(r1a, 1, 0); LDB(r1b, 1, 1); LDB(r1c, 1, 2);
        acc = __builtin_amdgcn_mfma_f32_32x32x16_f16(af[0], r0a, acc, 0, 0, 0);
        acc = __builtin_amdgcn_mfma_f32_32x32x16_f16(af[1], r0b, acc, 0, 0, 0);
        acc = __builtin_amdgcn_mfma_f32_32x32x16_f16(af[2], r0c, acc, 0, 0, 0);
        LDB(r2a, 2, 0); LDB(r2b, 2, 1); LDB(r2c, 2, 2);
        acc = __builtin_amdgcn_mfma_f32_32x32x16_f16(af[3], r1a, acc, 0, 0, 0);
        acc = __builtin_amdgcn_mfma_f32_32x32x16_f16(af[4], r1b, acc, 0, 0, 0);
        acc = __builtin_amdgcn_mfma_f32_32x32x16_f16(af[5], r1c, acc, 0, 0, 0);
        acc = __builtin_amdgcn_mfma_f32_32x32x16_f16(af[6], r2a, acc, 0, 0, 0);
        acc = __builtin_amdgcn_mfma_f32_32x32x16_f16(af[7], r2b, acc, 0, 0, 0);
        acc = __builtin_amdgcn_mfma_f32_32x32x16_f16(af[8], r2c, acc, 0, 0, 0);

        #pragma unroll
        for (int r = 0; r < 16; ++r) pool[r] += fmaxf(acc[r], 0.f);
    }
    #undef LDB

    #pragma unroll
    for (int m = 1; m <= 16; m <<= 1) {
        #pragma unroll
        for (int r = 0; r < 16; ++r) pool[r] += __shfl_xor(pool[r], m, 64);
    }
    if ((lane & 31) == 0) {
        #pragma unroll
        for (int r = 0; r < 16; ++r)
            atomicAdd(&s_pool[(r & 3) + 8*(r >> 2) + 4*(lane >> 5)], pool[r]);
    }
    __syncthreads();
    if (tid < C2) poolo[tid] = s_pool[tid];     // raw partial; prep scales
}

// ---------------------------------------------------------------------------
// K2a: prep — one block per (b,t). Sums the two pool halves, then
// feat[128] -> fused[64] -> gates_x[256]. 1536 blocks = full-GPU parallel.
// ---------------------------------------------------------------------------
__device__ __forceinline__ float sigm(float x){ return 1.f/(1.f + __expf(-x)); }
__device__ __forceinline__ float ftanh(float x){
    float xc = fminf(fmaxf(x, -15.f), 15.f);
    float e = __expf(2.f*xc);
    return (e - 1.f)/(e + 1.f);
}

__global__ __launch_bounds__(256)
void lstm_prep(const float* __restrict__ poolp_r, const float* __restrict__ poolp_m,
               const float* __restrict__ fus_w, const float* __restrict__ fus_b,
               const float* __restrict__ wf_ih,
               const float* __restrict__ bf_ih, const float* __restrict__ bf_hh,
               float* __restrict__ fusedg, float* __restrict__ gates_x)
{
    __shared__ __align__(16) float s_feat[128];
    __shared__ __align__(16) float s_fused[64];
    const int bt  = blockIdx.x;          // b*96 + t
    const int tid = threadIdx.x;

    if (tid < 32) {
        float r = (poolp_r[bt*C2 + tid] + poolp_r[(BT + bt)*C2 + tid]) * (1.f/1984.f);
        float m = (poolp_m[bt*C2 + tid] + poolp_m[(BT + bt)*C2 + tid]) * (1.f/1984.f);
        s_feat[tid]      = r;
        s_feat[32 + tid] = m;
        s_feat[64 + tid] = sqrtf(r*r + m*m);
        s_feat[96 + tid] = atan2f(m, r);
    }
    __syncthreads();

    if (tid < 64) {
        float acc = fus_b[tid];
        const float4* wv = reinterpret_cast<const float4*>(fus_w + tid*128);
        float a0=0.f, a1=0.f, a2=0.f, a3=0.f;
        #pragma unroll
        for (int q = 0; q < 32; ++q) {
            float4 w = wv[q];
            float4 f = *reinterpret_cast<const float4*>(s_feat + q*4);
            a0 += w.x*f.x; a1 += w.y*f.y; a2 += w.z*f.z; a3 += w.w*f.w;
        }
        float v = fmaxf(acc + (a0+a1) + (a2+a3), 0.f);
        s_fused[tid] = v;
        fusedg[bt*64 + tid] = v;
    }
    __syncthreads();

    {
        float acc = bf_ih[tid] + bf_hh[tid];
        const float4* wv = reinterpret_cast<const float4*>(wf_ih + tid*64);
        float a0=0.f, a1=0.f, a2=0.f, a3=0.f;
        #pragma unroll
        for (int q = 0; q < 16; ++q) {
            float4 w = wv[q];
            float4 f = *reinterpret_cast<const float4*>(s_fused + q*4);
            a0 += w.x*f.x; a1 += w.y*f.y; a2 += w.z*f.z; a3 += w.w*f.w;
        }
        gates_x[bt*256 + tid] = acc + (a0+a1) + (a2+a3);
    }
}

// ---------------------------------------------------------------------------
// K2b: scan (unchanged). Blocks 0..15: forward recurrence, one barrier/step,
// gates assembled in-wave via 3x shfl_xor, s_h double-buffered.
// Blocks 16..31: backward LSTM = one step on fused[b,len-1] from zero state.
// ---------------------------------------------------------------------------
__global__ __launch_bounds__(256, 1)
void lstm_scan(const float* __restrict__ gates_x, const float* __restrict__ fusedg,
               const int* __restrict__ lengths,
               const float* __restrict__ wf_hh,
               const float* __restrict__ wb_ih,
               const float* __restrict__ bb_ih, const float* __restrict__ bb_hh,
               float* __restrict__ last_f, float* __restrict__ hb0)
{
    const int tid = threadIdx.x;
    const int b   = blockIdx.x & 15;
    const int len = lengths[b];

    if (blockIdx.x < 16) {
        __shared__ __align__(16) float s_h[2][64];
        const int ln = tid & 63;
        const int w  = tid >> 6;
        const int q  = ln >> 4;            // gate: 0=i 1=f 2=g 3=o
        const int u  = w*16 + (ln & 15);   // hidden unit
        const int g  = q*64 + u;           // gate row

        float whh[64];
        #pragma unroll
        for (int j = 0; j < 64; j += 4) {
            float4 a = *reinterpret_cast<const float4*>(wf_hh + g*64 + j);
            whh[j]=a.x; whh[j+1]=a.y; whh[j+2]=a.z; whh[j+3]=a.w;
        }
        if (q == 0) s_h[0][u] = 0.f;
        __syncthreads();

        const float* gxp = gates_x + (b*TT)*256 + g;
        float gx = gxp[0];
        float creg = 0.f;
        for (int t = 0; t < TT; ++t) {
            float gxn = (t+1 < TT) ? gxp[(t+1)*256] : 0.f;

            const int cur = t & 1;
            float a0=0.f, a1=0.f, a2=0.f, a3=0.f;
            #pragma unroll
            for (int j = 0; j < 64; j += 4) {
                float4 hv = *reinterpret_cast<const float4*>(&s_h[cur][j]);
                a0 += whh[j]*hv.x;   a1 += whh[j+1]*hv.y;
                a2 += whh[j+2]*hv.z; a3 += whh[j+3]*hv.w;
            }
            float acc = gx + (a0+a1) + (a2+a3);

            float p1 = __shfl_xor(acc, 16, 64);   // gate q^1
            float p2 = __shfl_xor(acc, 32, 64);   // gate q^2
            float p3 = __shfl_xor(p1,  32, 64);   // gate q^3
            float g0 = (q==0)?acc : (q==1)?p1 : (q==2)?p2 : p3;
            float g1 = (q==1)?acc : (q==0)?p1 : (q==3)?p2 : p3;
            float g2 = (q==2)?acc : (q==3)?p1 : (q==0)?p2 : p3;
            float g3 = (q==3)?acc : (q==2)?p1 : (q==1)?p2 : p3;

            creg = sigm(g1)*creg + sigm(g0)*ftanh(g2);
            float h = sigm(g3)*ftanh(creg);

            if (q == 0) {
                s_h[cur^1][u] = h;
                if (t == len-1) last_f[b*64 + u] = h;
            }
            gx = gxn;
            __syncthreads();
        }
    } else {
        __shared__ __align__(16) float s_f[64];
        __shared__ float s_g[256];
        if (tid < 64) s_f[tid] = fusedg[(b*TT + (len-1))*64 + tid];
        __syncthreads();
        {
            float acc = bb_ih[tid] + bb_hh[tid];
            const float4* wv = reinterpret_cast<const float4*>(wb_ih + tid*64);
            float a0=0.f, a1=0.f, a2=0.f, a3=0.f;
            #pragma unroll
            for (int qq = 0; qq < 16; ++qq) {
                float4 wvv = wv[qq];
                float4 f = *reinterpret_cast<const float4*>(s_f + qq*4);
                a0 += wvv.x*f.x; a1 += wvv.y*f.y; a2 += wvv.z*f.z; a3 += wvv.w*f.w;
            }
            s_g[tid] = acc + (a0+a1) + (a2+a3);
        }
        __syncthreads();
        if (tid < 64) {
            float iv = sigm(s_g[tid]);            // f gate irrelevant: c0 = 0
            float gv = ftanh(s_g[128+tid]);
            float ov = sigm(s_g[192+tid]);
            hb0[b*64 + tid] = ov*ftanh(iv*gv);
        }
    }
}

// ---------------------------------------------------------------------------
// K3: out[b,k] = fc_b[k] + last_f[b,:].fc_w[k,0:64] + hb0[b,:].fc_w[k,64:128]
// ---------------------------------------------------------------------------
__global__ __launch_bounds__(256)
void final_fc_kernel(const float* __restrict__ last_f, const float* __restrict__ hb0,
                     const float* __restrict__ fc_w, const float* __restrict__ fc_b,
                     float* __restrict__ out)
{
    int t = threadIdx.x;
    if (t >= BB*NC) return;
    int b = t / NC, k = t % NC;
    float acc = fc_b[k];
    const float* w = fc_w + k*128;
    #pragma unroll
    for (int j = 0; j < 64; ++j) acc += last_f[b*64+j]*w[j];
    #pragma unroll
    for (int j = 0; j < 64; ++j) acc += hb0[b*64+j]*w[64+j];
    out[b*NC + k] = acc;
}

extern "C" void kernel_launch(void* const* d_in, const int* in_sizes, int n_in,
                              void* d_out, int out_size, void* d_ws, size_t ws_size,
                              hipStream_t stream)
{
    const float* x_real = (const float*)d_in[0];
    const float* x_imag = (const float*)d_in[1];
    const int*   lengths= (const int*)d_in[2];
    const float* c1r_w = (const float*)d_in[3];
    const float* c1r_b = (const float*)d_in[4];
    const float* c1i_w = (const float*)d_in[5];
    const float* c1i_b = (const float*)d_in[6];
    const float* c2r_w = (const float*)d_in[7];
    const float* c2r_b = (const float*)d_in[8];
    const float* c2i_w = (const float*)d_in[9];
    const float* c2i_b = (const float*)d_in[10];
    const float* fus_w = (const float*)d_in[11];
    const float* fus_b = (const float*)d_in[12];
    const float* wf_ih = (const float*)d_in[13];
    const float* wf_hh = (const float*)d_in[14];
    const float* bf_ih = (const float*)d_in[15];
    const float* bf_hh = (const float*)d_in[16];
    const float* wb_ih = (const float*)d_in[17];
    const float* wb_hh = (const float*)d_in[18];
    const float* bb_ih = (const float*)d_in[19];
    const float* bb_hh = (const float*)d_in[20];
    const float* fc_w  = (const float*)d_in[21];
    const float* fc_b  = (const float*)d_in[22];
    float* out = (float*)d_out;

    // ws layout (floats): poolp_r[2*BT*C2] | poolp_m[2*BT*C2] | fusedg[BT*64]
    //                   | gates_x[BT*256] | last_f | hb0   (~2.8 MB)
    float* ws      = (float*)d_ws;
    float* poolp_r = ws;
    float* poolp_m = poolp_r + 2*BT*C2;
    float* fusedg  = poolp_m + 2*BT*C2;
    float* gates_x = fusedg  + BT*64;
    float* last_f  = gates_x + BT*256;
    float* hb0     = last_f  + BB*LH;

    conv_pool_mfma<<<dim3(BT, 2, 2), 512, 0, stream>>>(
        x_real, x_imag, c1r_w, c1r_b, c1i_w, c1i_b,
        c2r_w, c2r_b, c2i_w, c2i_b, poolp_r, poolp_m);

    lstm_prep<<<BT, 256, 0, stream>>>(poolp_r, poolp_m, fus_w, fus_b,
                                      wf_ih, bf_ih, bf_hh, fusedg, gates_x);

    lstm_scan<<<32, 256, 0, stream>>>(gates_x, fusedg, lengths, wf_hh,
                                      wb_ih, bb_ih, bb_hh, last_f, hb0);

    final_fc_kernel<<<1, 256, 0, stream>>>(last_f, hb0, fc_w, fc_b, out);
}